// Round 9
// baseline (9186.509 us; speedup 1.0000x reference)
//
#include <hip/hip_runtime.h>

#define T_STEPS 1024
#define BATCH   256
#define DIM     128
#define HID     256
#define NGP     8                  // batch super-groups (32 rows each)
#define NSLICE  8                  // h-slice blocks per group
#define NBLOCK  (NGP * NSLICE)     // 64
#define BT      16                 // rows per stream (2 streams per block)
#define JW      (HID / NSLICE)     // 32 h-indices per block

// LDS layout (bytes) — identical to R5 (proven)
#define U_OFF    0        // [128][256] bf16, swizzled
#define W_OFF    65536    // [128][128] bf16, swizzled
#define WD_OFF   98304    // [32][256]  bf16, swizzled
#define H_OFF    114688   // [16][256]  bf16, swizzled (shared serially by streams)
#define C_OFF    122880   // [16][256]  bf16, swizzled
#define GST_OFF  131072   // [16][132] f32 gates staging
#define CS0_OFF  139520   // [16][33]  f32 Cs partial 0
#define CS1_OFF  141632   // [16][33]  f32 Cs partial 1
#define SMEM_TOTAL 143744

// pbuf u64 strides: [buf2][gp8][st2][slice8][row16][jj32]
#define SLICE_CH 512
#define ST_CH    (8 * SLICE_CH)     // 4096
#define GP_CH    (2 * ST_CH)        // 8192
#define BUF_CH   (NGP * GP_CH)      // 65536 u64 = 512 KiB

typedef float f32x4 __attribute__((ext_vector_type(4)));
typedef short bf16x8 __attribute__((ext_vector_type(8)));

__device__ __forceinline__ unsigned short f2bf(float f) {
    union { float f; unsigned u; } v; v.f = f;
    unsigned r = (v.u + 0x7fffu + ((v.u >> 16) & 1u)) >> 16;   // RNE
    return (unsigned short)r;
}
__device__ __forceinline__ float sigm(float v) { return 1.0f / (1.0f + __expf(-v)); }
__device__ __forceinline__ float tanh_fast(float v) {
    const float e = __expf(2.0f * v);
    return 1.0f - 2.0f / (e + 1.0f);
}
// lgkm-only barrier: LDS ordered, but vmem (publishes/probes) float across. [T3/T4]
__device__ __forceinline__ void lgkm_bar() {
    asm volatile("s_waitcnt lgkmcnt(0)" ::: "memory");
    __builtin_amdgcn_s_barrier();
    __builtin_amdgcn_sched_barrier(0);
}
__device__ __forceinline__ void probe8(const unsigned long long* sp, unsigned long long v[8]) {
    #pragma unroll
    for (int i = 0; i < 8; ++i)
        v[i] = __hip_atomic_load(sp + i, __ATOMIC_RELAXED, __HIP_MEMORY_SCOPE_AGENT);
    __builtin_amdgcn_sched_barrier(0);   // pin the issue point early
}

__global__ __launch_bounds__(512)
void tlstm_kernel(const float* __restrict__ x,
                  const float* __restrict__ dts,
                  const float* __restrict__ h0,
                  const float* __restrict__ c0,
                  const float* __restrict__ W,
                  const float* __restrict__ U,
                  const float* __restrict__ bvec,
                  const float* __restrict__ Wd,
                  const float* __restrict__ bd,
                  float* __restrict__ out,
                  unsigned long long* pbuf)   // 1 MiB in d_ws
{
    extern __shared__ char smem[];
    float* gates_st = (float*)(smem + GST_OFF);
    float* cs0      = (float*)(smem + CS0_OFF);
    float* cs1      = (float*)(smem + CS1_OFF);

    const int tid  = threadIdx.x;
    const int lane = tid & 63;
    const int wid  = tid >> 6;     // 0..7 (wave = consumer of slice wid)
    const int lrow = lane & 15;
    const int lkg  = lane >> 4;
    const int n0   = wid << 4;

    const int b_ = tid >> 5;       // 0..15 (row within stream tile)
    const int jj = tid & 31;

    const int gp = blockIdx.x >> 3;     // batch super-group
    const int s  = blockIdx.x & 7;      // h-slice
    const int jb = s * JW;

    // ---- one-time: weights -> LDS (bf16, XOR-swizzled: byte ^= (row&7)<<4) ----
    for (int idx = tid; idx < 128 * 256; idx += 512) {
        const int r = idx >> 8, k = idx & 255;
        const int urow = ((r >> 5) * HID) + jb + (r & 31);
        int bo = (r << 9) + (k << 1); bo ^= (r & 7) << 4;
        *(unsigned short*)(smem + U_OFF + bo) = f2bf(U[(size_t)urow * HID + k]);
    }
    for (int idx = tid; idx < 128 * 128; idx += 512) {
        const int r = idx >> 7, k = idx & 127;
        const int wrow = ((r >> 5) * HID) + jb + (r & 31);
        int bo = (r << 8) + (k << 1); bo ^= (r & 7) << 4;
        *(unsigned short*)(smem + W_OFF + bo) = f2bf(W[(size_t)wrow * DIM + k]);
    }
    for (int idx = tid; idx < 32 * 256; idx += 512) {
        const int r = idx >> 8, k = idx & 255;
        int bo = (r << 9) + (k << 1); bo ^= (r & 7) << 4;
        *(unsigned short*)(smem + WD_OFF + bo) = f2bf(Wd[(size_t)(jb + r) * HID + k]);
    }

    // ---- per-thread constants ----
    const float bI = bvec[jb + jj];
    const float bF = bvec[HID + jb + jj];
    const float bG = bvec[2 * HID + jb + jj];
    const float bO = bvec[3 * HID + jb + jj];
    const float bD = bd[jb + jj];

    // ---- prefetch x(0) raw + dt(0), both streams ----
    float4 xr[2][8];
    float dtv[2], dtn[2];
    #pragma unroll
    for (int st = 0; st < 2; ++st) {
        const float* xp = x + ((size_t)0 * BATCH + gp * 32 + st * 16 + lrow) * DIM + (lkg << 3);
        #pragma unroll
        for (int kc = 0; kc < 4; ++kc) {
            xr[st][2 * kc]     = *(const float4*)(xp + kc * 32);
            xr[st][2 * kc + 1] = *(const float4*)(xp + kc * 32 + 4);
        }
        dtv[st] = dts[(size_t)(gp * 32 + st * 16 + b_) * T_STEPS + 0];
        dtn[st] = dtv[st];
    }

    // ---- init: c regs + publish tagged h0/c0 (tag=1) into buf0, both streams ----
    float c_reg[2];
    #pragma unroll
    for (int st = 0; st < 2; ++st) {
        const int rowg = gp * 32 + st * 16 + b_;
        const float h0v = h0[(size_t)rowg * HID + jb + jj];
        const float c0v = c0[(size_t)rowg * HID + jb + jj];
        c_reg[st] = c0v;
        const unsigned long long pv = (1ull << 32)
            | ((unsigned)f2bf(h0v) << 16) | (unsigned)f2bf(c0v);
        const int ei = gp * GP_CH + st * ST_CH + s * SLICE_CH + b_ * 32 + jj;
        __hip_atomic_store(pbuf + ei, pv, __ATOMIC_RELAXED, __HIP_MEMORY_SCOPE_AGENT);
    }
    __syncthreads();   // full drain once: weights visible, publishes flushed

    // ---- prologue: issue probe for stream A, step 0 ----
    unsigned long long v[2][8];
    probe8(pbuf + gp * GP_CH + 0 * ST_CH + wid * SLICE_CH + lane * 8, v[0]);

    for (int t = 0; t < T_STEPS; ++t) {
        const int cur = t & 1;
        #pragma unroll
        for (int st = 0; st < 2; ++st) {
            const unsigned target = (unsigned)(t + 1);
            const unsigned long long* sp = pbuf + cur * BUF_CH + gp * GP_CH
                                         + st * ST_CH + wid * SLICE_CH + lane * 8;
            // ---- verify (waitcnt lands here; retry rare in steady state) ----
            for (;;) {
                bool ok = true;
                #pragma unroll
                for (int i = 0; i < 8; ++i)
                    ok = ok && ((unsigned)(v[st][i] >> 32) == target);
                if (__all((int)ok)) break;
                probe8(sp, v[st]);
            }
            // ---- stage: extract h,c -> swizzled LDS tile ----
            {
                bf16x8 hv, cv;
                #pragma unroll
                for (int i = 0; i < 8; ++i) {
                    hv[i] = (short)((unsigned short)(v[st][i] >> 16));
                    cv[i] = (short)((unsigned short)(v[st][i] & 0xffffu));
                }
                const int r  = lane >> 2;
                const int cb = (wid << 6) + ((lane & 3) << 4);
                int bo = (r << 9) + cb; bo ^= (r & 7) << 4;
                *(bf16x8*)(smem + H_OFF + bo) = hv;
                *(bf16x8*)(smem + C_OFF + bo) = cv;
            }
            lgkm_bar();   // tile staged (no vm drain)

            // ---- issue next probe a full phase early (RT hides under MFMA) ----
            if (st == 0) {
                probe8(pbuf + cur * BUF_CH + gp * GP_CH + ST_CH
                       + wid * SLICE_CH + lane * 8, v[1]);
            } else if (t < T_STEPS - 1) {
                probe8(pbuf + (cur ^ 1) * BUF_CH + gp * GP_CH
                       + wid * SLICE_CH + lane * 8, v[0]);
            }

            // ---- convert this stream's x to bf16 fragments ----
            bf16x8 xa[4];
            #pragma unroll
            for (int kc = 0; kc < 4; ++kc) {
                const float4 f0 = xr[st][2 * kc];
                const float4 f1 = xr[st][2 * kc + 1];
                bf16x8 a;
                a[0] = (short)f2bf(f0.x); a[1] = (short)f2bf(f0.y);
                a[2] = (short)f2bf(f0.z); a[3] = (short)f2bf(f0.w);
                a[4] = (short)f2bf(f1.x); a[5] = (short)f2bf(f1.y);
                a[6] = (short)f2bf(f1.z); a[7] = (short)f2bf(f1.w);
                xa[kc] = a;
            }
            // ---- prefetch x(t+1)/dt(t+1) during B phase (covered by mfmaB) ----
            // NOTE: dt goes to dtn[], NOT dtv[] — dtv[1] is still live for this
            // step's elementwise (R8 bug: clobbering dtv here used dt(t+1) for B).
            if (st == 1 && t < T_STEPS - 1) {
                #pragma unroll
                for (int ss = 0; ss < 2; ++ss) {
                    const float* xp = x + ((size_t)(t + 1) * BATCH + gp * 32 + ss * 16 + lrow) * DIM + (lkg << 3);
                    #pragma unroll
                    for (int kc = 0; kc < 4; ++kc) {
                        xr[ss][2 * kc]     = *(const float4*)(xp + kc * 32);
                        xr[ss][2 * kc + 1] = *(const float4*)(xp + kc * 32 + 4);
                    }
                    dtn[ss] = dts[(size_t)(gp * 32 + ss * 16 + b_) * T_STEPS + (t + 1)];
                }
            }

            // ---- MFMA: x@W^T + h@U^T (all waves), c@Wd^T (waves 0-3) ----
            f32x4 accX = {0.f, 0.f, 0.f, 0.f};
            f32x4 accH = {0.f, 0.f, 0.f, 0.f};
            {
                const int wr = n0 + lrow;
                #pragma unroll
                for (int kc = 0; kc < 4; ++kc) {
                    int wo = (wr << 8) + ((kc * 32 + (lkg << 3)) << 1); wo ^= (wr & 7) << 4;
                    const bf16x8 wv = *(const bf16x8*)(smem + W_OFF + wo);
                    accX = __builtin_amdgcn_mfma_f32_16x16x32_bf16(xa[kc], wv, accX, 0, 0, 0);
                }
                #pragma unroll
                for (int kc = 0; kc < 8; ++kc) {
                    int ao = (lrow << 9) + ((kc * 32 + (lkg << 3)) << 1); ao ^= (lrow & 7) << 4;
                    const bf16x8 av = *(const bf16x8*)(smem + H_OFF + ao);
                    int uo = (wr << 9) + ((kc * 32 + (lkg << 3)) << 1); uo ^= (wr & 7) << 4;
                    const bf16x8 uv = *(const bf16x8*)(smem + U_OFF + uo);
                    accH = __builtin_amdgcn_mfma_f32_16x16x32_bf16(av, uv, accH, 0, 0, 0);
                }
            }
            if (wid < 4) {
                f32x4 accC = {0.f, 0.f, 0.f, 0.f};
                const int nt = wid >> 1;
                const int kh = wid & 1;
                const int wr = (nt << 4) + lrow;
                #pragma unroll
                for (int kc = 0; kc < 4; ++kc) {
                    const int kk = kh * 4 + kc;
                    int ao = (lrow << 9) + ((kk * 32 + (lkg << 3)) << 1); ao ^= (lrow & 7) << 4;
                    const bf16x8 av = *(const bf16x8*)(smem + C_OFF + ao);
                    int wo = (wr << 9) + ((kk * 32 + (lkg << 3)) << 1); wo ^= (wr & 7) << 4;
                    const bf16x8 wv = *(const bf16x8*)(smem + WD_OFF + wo);
                    accC = __builtin_amdgcn_mfma_f32_16x16x32_bf16(av, wv, accC, 0, 0, 0);
                }
                float* dst = kh ? cs1 : cs0;
                #pragma unroll
                for (int i = 0; i < 4; ++i)
                    dst[((lkg << 2) + i) * 33 + (nt << 4) + lrow] = accC[i];
            }
            #pragma unroll
            for (int i = 0; i < 4; ++i)
                gates_st[((lkg << 2) + i) * 132 + n0 + lrow] = accX[i] + accH[i];

            lgkm_bar();   // gates staged (no vm drain)

            // ---- elementwise T-LSTM update (uses dtv[st] = dt(t), preserved) ----
            float cn, hn;
            {
                const float ipre = gates_st[b_ * 132 + jj]      + bI;
                const float fpre = gates_st[b_ * 132 + 32 + jj] + bF;
                const float gpre = gates_st[b_ * 132 + 64 + jj] + bG;
                const float opre = gates_st[b_ * 132 + 96 + jj] + bO;
                const float cspre = cs0[b_ * 33 + jj] + cs1[b_ * 33 + jj] + bD;
                const float gdt  = 1.0f / __logf(2.718281828459045f + dtv[st]);
                const float Cs    = tanh_fast(cspre);
                const float cstar = c_reg[st] - Cs + Cs * gdt;
                cn = sigm(fpre) * cstar + sigm(ipre) * tanh_fast(gpre);
                hn = sigm(opre) * tanh_fast(cn);
                c_reg[st] = cn;
            }

            const int rowg = gp * 32 + st * 16 + b_;
            if (t == T_STEPS - 1) {
                out[((size_t)t * BATCH + rowg) * HID + jb + jj] = hn;
                const size_t base = (size_t)T_STEPS * BATCH * HID;
                out[base + (size_t)rowg * HID + jb + jj] = hn;
                out[base + (size_t)BATCH * HID + (size_t)rowg * HID + jb + jj] = cn;
            } else {
                // publish tagged {h,c} (single store, fire-and-forget) + out
                const unsigned long long pv = ((unsigned long long)(unsigned)(t + 2) << 32)
                    | ((unsigned)f2bf(hn) << 16) | (unsigned)f2bf(cn);
                const int ei = (cur ^ 1) * BUF_CH + gp * GP_CH + st * ST_CH
                             + s * SLICE_CH + b_ * 32 + jj;
                __hip_atomic_store(pbuf + ei, pv, __ATOMIC_RELAXED, __HIP_MEMORY_SCOPE_AGENT);
                out[((size_t)t * BATCH + rowg) * HID + jb + jj] = hn;
            }

            // ---- opportunistic re-probe of A(t+1) at end of B phase ----
            if (st == 1 && t < T_STEPS - 1) {
                bool okA = true;
                #pragma unroll
                for (int i = 0; i < 8; ++i)
                    okA = okA && ((unsigned)(v[0][i] >> 32) == (unsigned)(t + 2));
                if (!__all((int)okA))
                    probe8(pbuf + (cur ^ 1) * BUF_CH + gp * GP_CH
                           + wid * SLICE_CH + lane * 8, v[0]);
            }
        }
        // roll prefetched dt into the live regs only after both phases consumed dt(t)
        dtv[0] = dtn[0];
        dtv[1] = dtn[1];
    }
}

extern "C" void kernel_launch(void* const* d_in, const int* in_sizes, int n_in,
                              void* d_out, int out_size, void* d_ws, size_t ws_size,
                              hipStream_t stream) {
    (void)in_sizes; (void)n_in; (void)out_size; (void)ws_size;
    const float* x   = (const float*)d_in[0];
    const float* dts = (const float*)d_in[1];
    const float* h0  = (const float*)d_in[2];
    const float* c0  = (const float*)d_in[3];
    const float* W   = (const float*)d_in[4];
    const float* U   = (const float*)d_in[5];
    const float* bv  = (const float*)d_in[6];
    const float* Wd  = (const float*)d_in[7];
    const float* bd  = (const float*)d_in[8];
    float* out = (float*)d_out;

    unsigned long long* pbuf = (unsigned long long*)d_ws;   // 1 MiB (R5-proven)

    hipMemsetAsync(pbuf, 0, (size_t)2 * BUF_CH * 8, stream);   // clear tags each launch
    hipFuncSetAttribute((const void*)tlstm_kernel,
                        hipFuncAttributeMaxDynamicSharedMemorySize, SMEM_TOTAL);
    tlstm_kernel<<<dim3(NBLOCK), dim3(512), SMEM_TOTAL, stream>>>(
        x, dts, h0, c0, W, U, bv, Wd, bd, out, pbuf);
}

// Round 10
// 5178.535 us; speedup vs baseline: 1.7740x; 1.7740x over previous
//
#include <hip/hip_runtime.h>

#define T_STEPS 1024
#define BATCH   256
#define DIM     128
#define HID     256
#define NSLICE  8                  // blocks per batch-group (h-slice split)
#define BT      16                 // batch tile per group
#define NGROUP  (BATCH / BT)       // 16
#define NBLOCK  (NGROUP * NSLICE)  // 128
#define JW      (HID / NSLICE)     // 32 h-indices per block

// LDS layout (bytes) — R5-proven
#define U_OFF    0        // [128][256] bf16, swizzled
#define W_OFF    65536    // [128][128] bf16, swizzled
#define WD_OFF   98304    // [32][256]  bf16, swizzled
#define H_OFF    114688   // [16][256]  bf16, swizzled
#define C_OFF    122880   // [16][256]  bf16, swizzled
#define GST_OFF  131072   // [16][132] f32 gates staging (padded stride)
#define CS0_OFF  139520   // [16][33]  f32 Cs partial 0
#define CS1_OFF  141632   // [16][33]  f32 Cs partial 1
#define SMEM_TOTAL 143744

typedef float f32x4 __attribute__((ext_vector_type(4)));
typedef short bf16x8 __attribute__((ext_vector_type(8)));

__device__ __forceinline__ unsigned short f2bf(float f) {
    union { float f; unsigned u; } v; v.f = f;
    unsigned r = (v.u + 0x7fffu + ((v.u >> 16) & 1u)) >> 16;   // RNE
    return (unsigned short)r;
}
__device__ __forceinline__ float sigm(float v) { return 1.0f / (1.0f + __expf(-v)); }
__device__ __forceinline__ float tanh_fast(float v) {
    const float e = __expf(2.0f * v);
    return 1.0f - 2.0f / (e + 1.0f);
}

__global__ __launch_bounds__(512)
void tlstm_kernel(const float* __restrict__ x,
                  const float* __restrict__ dts,
                  const float* __restrict__ h0,
                  const float* __restrict__ c0,
                  const float* __restrict__ W,
                  const float* __restrict__ U,
                  const float* __restrict__ bvec,
                  const float* __restrict__ Wd,
                  const float* __restrict__ bd,
                  float* __restrict__ out,
                  unsigned long long* pbuf)   // [2][16][8][16][32] u64 = 1 MiB
{
    extern __shared__ char smem[];
    float* gates_st = (float*)(smem + GST_OFF);
    float* cs0      = (float*)(smem + CS0_OFF);
    float* cs1      = (float*)(smem + CS1_OFF);

    const int tid = threadIdx.x;
    const int g  = blockIdx.x / NSLICE;   // batch group
    const int s  = blockIdx.x % NSLICE;   // h-slice
    const int bb = g * BT;
    const int jb = s * JW;

    const int lane = tid & 63;
    const int wid  = tid >> 6;     // 0..7
    const int lrow = lane & 15;    // A-row(batch) / B-col(weight row) / D-col
    const int lkg  = lane >> 4;    // K-group 0..3
    const int n0   = wid << 4;     // gates column base for this wave

    const int b_ = tid >> 5;   // 0..15 batch row (elementwise + publish mapping)
    const int jj = tid & 31;   // 0..31 h-index within slice

    // ---- one-time: weights -> LDS (bf16, XOR-swizzled rows: byte ^= (row&7)<<4) ----
    for (int idx = tid; idx < 128 * 256; idx += 512) {
        const int r = idx >> 8, k = idx & 255;
        const int urow = ((r >> 5) * HID) + jb + (r & 31);   // q*H + jb + jj
        int bo = (r << 9) + (k << 1); bo ^= (r & 7) << 4;
        *(unsigned short*)(smem + U_OFF + bo) = f2bf(U[(size_t)urow * HID + k]);
    }
    for (int idx = tid; idx < 128 * 128; idx += 512) {
        const int r = idx >> 7, k = idx & 127;
        const int wrow = ((r >> 5) * HID) + jb + (r & 31);
        int bo = (r << 8) + (k << 1); bo ^= (r & 7) << 4;
        *(unsigned short*)(smem + W_OFF + bo) = f2bf(W[(size_t)wrow * DIM + k]);
    }
    for (int idx = tid; idx < 32 * 256; idx += 512) {
        const int r = idx >> 8, k = idx & 255;
        int bo = (r << 9) + (k << 1); bo ^= (r & 7) << 4;
        *(unsigned short*)(smem + WD_OFF + bo) = f2bf(Wd[(size_t)(jb + r) * HID + k]);
    }

    // ---- per-thread constants ----
    const float bI = bvec[jb + jj];
    const float bF = bvec[HID + jb + jj];
    const float bG = bvec[2 * HID + jb + jj];
    const float bO = bvec[3 * HID + jb + jj];
    const float bD = bd[jb + jj];

    // ---- prefetch x(0) raw + dt(0) ----
    float4 xr[8];
    float dt_cur;
    {
        const float* xp = x + ((size_t)0 * BATCH + bb + lrow) * DIM + (lkg << 3);
        #pragma unroll
        for (int kc = 0; kc < 4; ++kc) {
            xr[2 * kc]     = *(const float4*)(xp + kc * 32);
            xr[2 * kc + 1] = *(const float4*)(xp + kc * 32 + 4);
        }
        dt_cur = dts[(size_t)(bb + b_) * T_STEPS + 0];
    }

    // ---- init: c in register + publish tagged h0/c0 (tag=1) into buf0 ----
    float c_reg;
    {
        const float h0v = h0[(size_t)(bb + b_) * HID + jb + jj];
        const float c0v = c0[(size_t)(bb + b_) * HID + jb + jj];
        c_reg = c0v;
        const unsigned long long pv = (1ull << 32)
            | ((unsigned)f2bf(h0v) << 16) | (unsigned)f2bf(c0v);
        const size_t ei = (((size_t)0 * NGROUP + g) * NSLICE + s) * 512 + b_ * 32 + jj;
        __hip_atomic_store(pbuf + ei, pv, __ATOMIC_RELAXED, __HIP_MEMORY_SCOPE_AGENT);
    }

    for (int t = 0; t < T_STEPS; ++t) {
        const int cur = t & 1;

        // ---- (1) x-dependent work first: convert + x@W^T MFMAs (no poll dep) ----
        bf16x8 xa[4];
        #pragma unroll
        for (int kc = 0; kc < 4; ++kc) {
            const float4 f0 = xr[2 * kc];
            const float4 f1 = xr[2 * kc + 1];
            bf16x8 a;
            a[0] = (short)f2bf(f0.x); a[1] = (short)f2bf(f0.y);
            a[2] = (short)f2bf(f0.z); a[3] = (short)f2bf(f0.w);
            a[4] = (short)f2bf(f1.x); a[5] = (short)f2bf(f1.y);
            a[6] = (short)f2bf(f1.z); a[7] = (short)f2bf(f1.w);
            xa[kc] = a;
        }
        f32x4 accX = {0.f, 0.f, 0.f, 0.f};
        {
            const int wr = n0 + lrow;
            #pragma unroll
            for (int kc = 0; kc < 4; ++kc) {       // x @ W^T, K=128
                int wo = (wr << 8) + ((kc * 32 + (lkg << 3)) << 1); wo ^= (wr & 7) << 4;
                const bf16x8 wv = *(const bf16x8*)(smem + W_OFF + wo);
                accX = __builtin_amdgcn_mfma_f32_16x16x32_bf16(xa[kc], wv, accX, 0, 0, 0);
            }
        }

        // ---- (2) low-traffic poll: 1 sample u64 per lane covers all 64 lines ----
        const unsigned target = (unsigned)(t + 1);
        const unsigned long long* sp = pbuf
            + (((size_t)cur * NGROUP + g) * NSLICE + wid) * 512
            + ((lane >> 2) * 32 + ((lane & 3) << 3));
        {
            unsigned long long sv;
            do {
                sv = __hip_atomic_load(sp + 7, __ATOMIC_RELAXED, __HIP_MEMORY_SCOPE_AGENT);
            } while (!__all((int)((unsigned)(sv >> 32) == target)));
        }
        // ---- (2b) full fetch + tag verify (retry ~never after sample fire) ----
        unsigned long long v[8];
        {
            bool ok;
            do {
                #pragma unroll
                for (int i = 0; i < 8; ++i)
                    v[i] = __hip_atomic_load(sp + i, __ATOMIC_RELAXED, __HIP_MEMORY_SCOPE_AGENT);
                ok = true;
                #pragma unroll
                for (int i = 0; i < 8; ++i)
                    ok = ok && ((unsigned)(v[i] >> 32) == target);
            } while (!__all((int)ok));
        }

        // ---- (3) extract h,c and stage into swizzled LDS tiles ----
        {
            bf16x8 hv, cv;
            #pragma unroll
            for (int i = 0; i < 8; ++i) {
                hv[i] = (short)((unsigned short)(v[i] >> 16));
                cv[i] = (short)((unsigned short)(v[i] & 0xffffu));
            }
            const int r  = lane >> 2;                       // batch row 0..15
            const int cb = (wid << 6) + ((lane & 3) << 4);  // byte col base
            int bo = (r << 9) + cb; bo ^= (r & 7) << 4;
            *(bf16x8*)(smem + H_OFF + bo) = hv;
            *(bf16x8*)(smem + C_OFF + bo) = cv;
        }
        __syncthreads();   // #1: all slices staged

        // ---- (4) h @ U^T (all waves) + c @ Wd^T (waves 0-3) ----
        f32x4 accH = {0.f, 0.f, 0.f, 0.f};
        {
            const int wr = n0 + lrow;
            #pragma unroll
            for (int kc = 0; kc < 8; ++kc) {       // h @ U^T, K=256
                int ao = (lrow << 9) + ((kc * 32 + (lkg << 3)) << 1); ao ^= (lrow & 7) << 4;
                const bf16x8 av = *(const bf16x8*)(smem + H_OFF + ao);
                int uo = (wr << 9) + ((kc * 32 + (lkg << 3)) << 1); uo ^= (wr & 7) << 4;
                const bf16x8 uv = *(const bf16x8*)(smem + U_OFF + uo);
                accH = __builtin_amdgcn_mfma_f32_16x16x32_bf16(av, uv, accH, 0, 0, 0);
            }
        }
        if (wid < 4) {
            f32x4 accC = {0.f, 0.f, 0.f, 0.f};
            const int nt = wid >> 1;               // N-tile 0/1 (cols 0-15 / 16-31)
            const int kh = wid & 1;                // K-half
            const int wr = (nt << 4) + lrow;
            #pragma unroll
            for (int kc = 0; kc < 4; ++kc) {
                const int kk = kh * 4 + kc;
                int ao = (lrow << 9) + ((kk * 32 + (lkg << 3)) << 1); ao ^= (lrow & 7) << 4;
                const bf16x8 av = *(const bf16x8*)(smem + C_OFF + ao);
                int wo = (wr << 9) + ((kk * 32 + (lkg << 3)) << 1); wo ^= (wr & 7) << 4;
                const bf16x8 wv = *(const bf16x8*)(smem + WD_OFF + wo);
                accC = __builtin_amdgcn_mfma_f32_16x16x32_bf16(av, wv, accC, 0, 0, 0);
            }
            float* dst = kh ? cs1 : cs0;
            #pragma unroll
            for (int i = 0; i < 4; ++i)
                dst[((lkg << 2) + i) * 33 + (nt << 4) + lrow] = accC[i];
        }
        #pragma unroll
        for (int i = 0; i < 4; ++i)   // D: row=(lane>>4)*4+i (batch), col=lane&15
            gates_st[((lkg << 2) + i) * 132 + n0 + lrow] = accX[i] + accH[i];

        __syncthreads();   // #2: gates staged

        // ---- (5) elementwise T-LSTM update ----
        float cn, hn;
        {
            const float ipre = gates_st[b_ * 132 + jj]      + bI;
            const float fpre = gates_st[b_ * 132 + 32 + jj] + bF;
            const float gpre = gates_st[b_ * 132 + 64 + jj] + bG;
            const float opre = gates_st[b_ * 132 + 96 + jj] + bO;
            const float cspre = cs0[b_ * 33 + jj] + cs1[b_ * 33 + jj] + bD;
            const float gdt  = 1.0f / __logf(2.718281828459045f + dt_cur);
            const float Cs    = tanh_fast(cspre);
            const float cstar = c_reg - Cs + Cs * gdt;
            cn = sigm(fpre) * cstar + sigm(ipre) * tanh_fast(gpre);
            hn = sigm(opre) * tanh_fast(cn);
            c_reg = cn;
        }

        if (t == T_STEPS - 1) {
            out[((size_t)t * BATCH + bb + b_) * HID + jb + jj] = hn;
            const size_t base = (size_t)T_STEPS * BATCH * HID;
            out[base + (size_t)(bb + b_) * HID + jb + jj] = hn;
            out[base + (size_t)BATCH * HID + (size_t)(bb + b_) * HID + jb + jj] = cn;
            break;
        }

        // ---- (6) publish tagged {h,c}: ONE atomic u64, fire-and-forget ----
        {
            const unsigned long long pv = ((unsigned long long)(unsigned)(t + 2) << 32)
                | ((unsigned)f2bf(hn) << 16) | (unsigned)f2bf(cn);
            const size_t ei = (((size_t)(cur ^ 1) * NGROUP + g) * NSLICE + s) * 512
                            + b_ * 32 + jj;
            __hip_atomic_store(pbuf + ei, pv, __ATOMIC_RELAXED, __HIP_MEMORY_SCOPE_AGENT);
        }

        // ---- (7) off-path: out store + prefetch x(t+1), dt(t+1) ----
        out[((size_t)t * BATCH + bb + b_) * HID + jb + jj] = hn;
        {
            const float* xp = x + ((size_t)(t + 1) * BATCH + bb + lrow) * DIM + (lkg << 3);
            #pragma unroll
            for (int kc = 0; kc < 4; ++kc) {
                xr[2 * kc]     = *(const float4*)(xp + kc * 32);
                xr[2 * kc + 1] = *(const float4*)(xp + kc * 32 + 4);
            }
            dt_cur = dts[(size_t)(bb + b_) * T_STEPS + (t + 1)];
        }
    }
}

extern "C" void kernel_launch(void* const* d_in, const int* in_sizes, int n_in,
                              void* d_out, int out_size, void* d_ws, size_t ws_size,
                              hipStream_t stream) {
    (void)in_sizes; (void)n_in; (void)out_size; (void)ws_size;
    const float* x   = (const float*)d_in[0];
    const float* dts = (const float*)d_in[1];
    const float* h0  = (const float*)d_in[2];
    const float* c0  = (const float*)d_in[3];
    const float* W   = (const float*)d_in[4];
    const float* U   = (const float*)d_in[5];
    const float* bv  = (const float*)d_in[6];
    const float* Wd  = (const float*)d_in[7];
    const float* bd  = (const float*)d_in[8];
    float* out = (float*)d_out;

    // pbuf: [2][16][8][16][32] u64 = 1 MiB of workspace
    unsigned long long* pbuf = (unsigned long long*)d_ws;
    const size_t pbuf_bytes = 2ull * NGROUP * NSLICE * 512 * 8;

    // reset tags each launch (stale tags from a prior replay must not false-match)
    hipMemsetAsync(pbuf, 0, pbuf_bytes, stream);
    hipFuncSetAttribute((const void*)tlstm_kernel,
                        hipFuncAttributeMaxDynamicSharedMemorySize, SMEM_TOTAL);
    tlstm_kernel<<<dim3(NBLOCK), dim3(512), SMEM_TOTAL, stream>>>(
        x, dts, h0, c0, W, U, bv, Wd, bd, out, pbuf);
}